// Round 1
// baseline (468.351 us; speedup 1.0000x reference)
//
#include <hip/hip_runtime.h>
#include <hip/hip_bf16.h>

#define NN 8192
#define FIN 512
#define FOUT 256
#define JTILE 64

typedef __attribute__((ext_vector_type(8))) short short8;
typedef __attribute__((ext_vector_type(4))) float float4v;
typedef __attribute__((ext_vector_type(16))) float float16v;

#if __has_builtin(__builtin_amdgcn_exp2f)
#define EXP2(x) __builtin_amdgcn_exp2f(x)
#else
#define EXP2(x) exp2f(x)
#endif

__device__ __forceinline__ short f2bf(float f) {
    union { float f; unsigned u; } v; v.f = f;
    unsigned r = (v.u + 0x7FFFu + ((v.u >> 16) & 1u)) >> 16;
    return (short)r;
}

// ---------------- Kernel 0: Wt[n][k] = bf16(W[k][n]), tiled transpose ----------------
__global__ __launch_bounds__(256) void wt_kernel(const float* __restrict__ W,
                                                 short* __restrict__ Wt) {
    __shared__ short tile[32][33];
    int tx = threadIdx.x & 31, ty = threadIdx.x >> 5;   // 32 x 8
    int k0 = blockIdx.x * 32, n0 = blockIdx.y * 32;
#pragma unroll
    for (int r = 0; r < 32; r += 8)
        tile[ty + r][tx] = f2bf(W[(size_t)(k0 + ty + r) * FOUT + n0 + tx]);
    __syncthreads();
#pragma unroll
    for (int r = 0; r < 32; r += 8)
        Wt[(size_t)(n0 + ty + r) * FIN + k0 + tx] = tile[tx][ty + r];
}

// ---------------- Kernel 1: h_t[n][m] = bf16((x@W)[m][n]); fused f_src/f_dst ----------------
__global__ __launch_bounds__(256) void h_kernel(const float* __restrict__ x,
                                                const short* __restrict__ Wt,
                                                const float* __restrict__ a,
                                                short* __restrict__ h_t,
                                                float* __restrict__ f_src,
                                                float* __restrict__ f_dst) {
    int wave = (blockIdx.x << 2) + (threadIdx.x >> 6);
    int lane = threadIdx.x & 63;
    int m0 = (wave & 511) << 4;
    int n0 = (wave >> 9) << 6;
    int lr = lane & 15, lq = lane >> 4;

    const float* xrow = x + (size_t)(m0 + lr) * FIN + lq * 8;
    const short* wbase = Wt + (size_t)(n0 + lr) * FIN + lq * 8;

    float4v acc[4] = {};
    for (int k0 = 0; k0 < FIN; k0 += 32) {
        float4v xa = *(const float4v*)(xrow + k0);
        float4v xb = *(const float4v*)(xrow + k0 + 4);
        short8 av;
        av[0] = f2bf(xa[0]); av[1] = f2bf(xa[1]); av[2] = f2bf(xa[2]); av[3] = f2bf(xa[3]);
        av[4] = f2bf(xb[0]); av[5] = f2bf(xb[1]); av[6] = f2bf(xb[2]); av[7] = f2bf(xb[3]);
#pragma unroll
        for (int ct = 0; ct < 4; ct++) {
            short8 bv = *(const short8*)(wbase + (size_t)ct * 16 * FIN + k0);
            acc[ct] = __builtin_amdgcn_mfma_f32_16x16x32_bf16(av, bv, acc[ct], 0, 0, 0);
        }
    }
    float s_part[4] = {0.f, 0.f, 0.f, 0.f};
    float d_part[4] = {0.f, 0.f, 0.f, 0.f};
#pragma unroll
    for (int ct = 0; ct < 4; ct++) {
        int n = n0 + ct * 16 + lr;
        float al = a[n], ar = a[FOUT + n];
#pragma unroll
        for (int reg = 0; reg < 4; reg++) {
            float hv = acc[ct][reg];
            s_part[reg] = fmaf(hv, al, s_part[reg]);
            d_part[reg] = fmaf(hv, ar, d_part[reg]);
            h_t[(size_t)n * NN + (m0 + lq * 4 + reg)] = f2bf(hv);
        }
    }
#pragma unroll
    for (int off = 1; off < 16; off <<= 1) {
#pragma unroll
        for (int reg = 0; reg < 4; reg++) {
            s_part[reg] += __shfl_xor(s_part[reg], off);
            d_part[reg] += __shfl_xor(d_part[reg], off);
        }
    }
    const float LOG2E = 1.4426950408889634f;
    if (lr == 0) {
#pragma unroll
        for (int reg = 0; reg < 4; reg++) {
            atomicAdd(&f_src[m0 + lq * 4 + reg], s_part[reg] * LOG2E);
            atomicAdd(&f_dst[m0 + lq * 4 + reg], d_part[reg] * LOG2E);
        }
    }
}

// ---------------- Kernel 2: fused masked-softmax-numerator @ h (j-sliced) ----------------
// Restructured: no Ht LDS staging (B operands direct from L2-resident h_t),
// double-buffered swizzled Pt + ONE non-draining barrier per tile,
// adj register-prefetched a full tile ahead (HBM latency ~900cy covered).
__global__ __launch_bounds__(256, 3) void gat_kernel(const int* __restrict__ adj,
                                                     const short* __restrict__ h_t,
                                                     const float* __restrict__ f_src,
                                                     const float* __restrict__ f_dst,
                                                     float* __restrict__ Opart,
                                                     float* __restrict__ lpart,
                                                     int jlen) {
    __shared__ short Pt[2][64 * 64];   // [row][j], XOR-swizzled (byte ^= (row&7)<<4), 2x8KB
    __shared__ float Fd[2][64];        // f_dst tile, double-buffered

    const int t = threadIdx.x;
    const int i0 = blockIdx.x * 64;
    const int slice = blockIdx.y;
    const int jbase = slice * jlen;

    const int prow = t >> 2, pjq = t & 3;            // P-compute role: 64 rows x 4 j-quads
    const int lane = t & 63, w = t >> 6;
    const int l31 = lane & 31, lq = lane >> 5;
    const int wn0 = w * 64;                          // wave's feature base

    const float fs = f_src[i0 + prow];
    const int* adjRow = adj + (size_t)(i0 + prow) * NN + jbase;
    // B-operand rows (feature rows of h_t); lq*8 folded in
    const short* hb0 = h_t + (size_t)(wn0 + l31) * NN + jbase + lq * 8;
    const short* hb1 = hb0 + (size_t)32 * NN;

    float16v acc00 = {}, acc01 = {}, acc10 = {}, acc11 = {};
    float lp = 0.f;

    // prologue: stage Fd[0], prefetch first adj tile
    if (t < 16) *(float4*)&Fd[0][t * 4] = *(const float4*)(f_dst + jbase + t * 4);
    int4 av0 = *(const int4*)(adjRow + pjq * 16);
    int4 av1 = *(const int4*)(adjRow + pjq * 16 + 4);
    int4 av2 = *(const int4*)(adjRow + pjq * 16 + 8);
    int4 av3 = *(const int4*)(adjRow + pjq * 16 + 12);
    __syncthreads();

    int buf = 0;
    const int pswz = (prow & 7) << 4;
    const int rswz = (l31 & 7) << 4;
    const int wb = prow * 128 + pjq * 32;            // byte offset of this thread's P chunk

    for (int jo = 0; jo < jlen; jo += JTILE) {
        // ---- phase A ----
        // issue B loads for THIS tile first (L2 latency hides under P compute)
        short8 b0[4], b1[4];
#pragma unroll
        for (int kk = 0; kk < 4; kk++) {
            b0[kk] = *(const short8*)(hb0 + jo + kk * 16);
            b1[kk] = *(const short8*)(hb1 + jo + kk * 16);
        }
        // issue NEXT tile's adj prefetch early (address clamped on last iter; no branch)
        const bool more = (jo + JTILE) < jlen;
        const int* ap = adjRow + (more ? jo + JTILE : 0) + pjq * 16;
        int4 an0 = *(const int4*)(ap);
        int4 an1 = *(const int4*)(ap + 4);
        int4 an2 = *(const int4*)(ap + 8);
        int4 an3 = *(const int4*)(ap + 12);

        // P compute (log2-domain scores; leaky_relu commutes with positive scaling)
        {
            const float4v fd0 = *(const float4v*)&Fd[buf][pjq * 16];
            const float4v fd1 = *(const float4v*)&Fd[buf][pjq * 16 + 4];
            const float4v fd2 = *(const float4v*)&Fd[buf][pjq * 16 + 8];
            const float4v fd3 = *(const float4v*)&Fd[buf][pjq * 16 + 12];
            short8 pbl, pbh;
#define PEL(A, FDV, DST, IDX)                              \
            {                                              \
                float y = fs + (FDV);                      \
                y = fmaxf(y, 0.2f * y);                    \
                float p = ((A) != 0) ? EXP2(y) : 0.f;      \
                lp += p;                                   \
                DST[IDX] = f2bf(p);                        \
            }
            PEL(av0.x, fd0[0], pbl, 0) PEL(av0.y, fd0[1], pbl, 1)
            PEL(av0.z, fd0[2], pbl, 2) PEL(av0.w, fd0[3], pbl, 3)
            PEL(av1.x, fd1[0], pbl, 4) PEL(av1.y, fd1[1], pbl, 5)
            PEL(av1.z, fd1[2], pbl, 6) PEL(av1.w, fd1[3], pbl, 7)
            PEL(av2.x, fd2[0], pbh, 0) PEL(av2.y, fd2[1], pbh, 1)
            PEL(av2.z, fd2[2], pbh, 2) PEL(av2.w, fd2[3], pbh, 3)
            PEL(av3.x, fd3[0], pbh, 4) PEL(av3.y, fd3[1], pbh, 5)
            PEL(av3.z, fd3[2], pbh, 6) PEL(av3.w, fd3[3], pbh, 7)
#undef PEL
            char* pbuf = (char*)&Pt[buf][0];
            *(short8*)(pbuf + (wb ^ pswz)) = pbl;
            *(short8*)(pbuf + ((wb + 16) ^ pswz)) = pbh;
        }
        // Fd prefetch for next tile (clamped; last-iter write is never read)
        if (t < 16) {
            float4 fdn = *(const float4*)(f_dst + jbase + (more ? jo + JTILE : 0) + t * 4);
            *(float4*)&Fd[buf ^ 1][t * 4] = fdn;
        }

        // single barrier per tile: drain LDS only, keep global prefetches in flight
        asm volatile("s_waitcnt lgkmcnt(0)\n\ts_barrier" ::: "memory");

        // ---- phase B: 4 k-steps of 16, A from swizzled Pt, B from regs ----
        {
            const char* pbuf = (const char*)&Pt[buf][0];
            const int ra = l31 * 128 + lq * 16;
#pragma unroll
            for (int kk = 0; kk < 4; kk++) {
                short8 a0 = *(const short8*)(pbuf + ((ra + kk * 32) ^ rswz));
                short8 a1 = *(const short8*)(pbuf + ((ra + 4096 + kk * 32) ^ rswz));
                acc00 = __builtin_amdgcn_mfma_f32_32x32x16_bf16(a0, b0[kk], acc00, 0, 0, 0);
                acc01 = __builtin_amdgcn_mfma_f32_32x32x16_bf16(a0, b1[kk], acc01, 0, 0, 0);
                acc10 = __builtin_amdgcn_mfma_f32_32x32x16_bf16(a1, b0[kk], acc10, 0, 0, 0);
                acc11 = __builtin_amdgcn_mfma_f32_32x32x16_bf16(a1, b1[kk], acc11, 0, 0, 0);
            }
        }
        av0 = an0; av1 = an1; av2 = an2; av3 = an3;
        buf ^= 1;
    }

    // ---- epilogue: partial row-sum l, partial O ----
    lp += __shfl_xor(lp, 1);
    lp += __shfl_xor(lp, 2);
    if (pjq == 0) lpart[slice * NN + i0 + prow] = lp;

    float* obase = Opart + ((size_t)slice * NN + i0) * FOUT;
    // C/D 32x32: col = l31, row = (reg&3) + 8*(reg>>2) + 4*lq
#pragma unroll
    for (int rt = 0; rt < 2; rt++) {
#pragma unroll
        for (int nt = 0; nt < 2; nt++) {
            const float16v& av = rt == 0 ? (nt == 0 ? acc00 : acc01) : (nt == 0 ? acc10 : acc11);
#pragma unroll
            for (int reg = 0; reg < 16; reg++) {
                int row = rt * 32 + (reg & 3) + 8 * (reg >> 2) + 4 * lq;
                int n = wn0 + nt * 32 + l31;
                obase[(size_t)row * FOUT + n] = av[reg];
            }
        }
    }
}

// ---------------- Kernel 3: combine partials: out = sum_s O_s / sum_s l_s ----------------
__global__ __launch_bounds__(256) void combine_kernel(const float* __restrict__ Opart,
                                                      const float* __restrict__ lpart,
                                                      float* __restrict__ out, int slices) {
    int i = blockIdx.x, n = threadIdx.x;
    float o = 0.f, l = 0.f;
    for (int s = 0; s < slices; s++) {
        o += Opart[((size_t)s * NN + i) * FOUT + n];
        l += lpart[s * NN + i];
    }
    out[(size_t)i * FOUT + n] = o / l;
}

extern "C" void kernel_launch(void* const* d_in, const int* in_sizes, int n_in,
                              void* d_out, int out_size, void* d_ws, size_t ws_size,
                              hipStream_t stream) {
    const float* x   = (const float*)d_in[0];
    const int*   adj = (const int*)d_in[1];
    const float* W   = (const float*)d_in[2];
    const float* a   = (const float*)d_in[3];
    float* out = (float*)d_out;

    char* ws = (char*)d_ws;
    short* h_t   = (short*)ws;                                   // 4 MB
    short* Wt    = (short*)(ws + (4u << 20));                    // 256 KB
    float* f_src = (float*)(ws + (4u << 20) + (256u << 10));     // 32 KB
    float* f_dst = (float*)(ws + (4u << 20) + (288u << 10));     // 32 KB
    float* lpart = (float*)(ws + (4u << 20) + (320u << 10));     // up to 256 KB (8 slices)
    float* Opart = (float*)(ws + (5u << 20));                    // up to 64 MB

    const size_t OSLICE = (size_t)NN * FOUT * 4;                 // 8 MB per slice
    int slices = 1;
    if (ws_size >= (size_t)(5u << 20) + 8 * OSLICE) slices = 8;
    else if (ws_size >= (size_t)(5u << 20) + 4 * OSLICE) slices = 4;
    else if (ws_size >= (size_t)(5u << 20) + 2 * OSLICE) slices = 2;
    int jlen = NN / slices;

    hipMemsetAsync(f_src, 0, 2 * NN * sizeof(float), stream);
    wt_kernel<<<dim3(FIN / 32, FOUT / 32), 256, 0, stream>>>(W, Wt);
    h_kernel<<<512, 256, 0, stream>>>(x, Wt, a, h_t, f_src, f_dst);
    gat_kernel<<<dim3(NN / 64, slices), 256, 0, stream>>>(adj, h_t, f_src, f_dst,
                                                          Opart, lpart, jlen);
    combine_kernel<<<NN, 256, 0, stream>>>(Opart, lpart, out, slices);
}